// Round 7
// baseline (240.716 us; speedup 1.0000x reference)
//
#include <hip/hip_runtime.h>

#define TPB 256
#define CPB 128                     // cells per block
#define PRED_CH 30
#define GT_CH 25
#define PF4 (CPB * PRED_CH / 4)     // 960 float4 per pred tile
#define GF4 (CPB * GT_CH / 4)       // 800 float4 per gt tile

// IEEE-exact helpers: prevent fma contraction so the IoU chain matches numpy
// float32 bit-for-bit (argmax flips would cost absmax=1.0 on obj_ij).
__device__ __forceinline__ float mul_rn(float a, float b) { return __fmul_rn(a, b); }
__device__ __forceinline__ float add_rn(float a, float b) { return __fadd_rn(a, b); }
__device__ __forceinline__ float sub_rn(float a, float b) { return __fsub_rn(a, b); }

// async global->LDS, 16B per lane (wave-uniform base + lane*16 dest — the
// HW-supported pattern, m104).
__device__ __forceinline__ void load_lds16(const void* g, void* l) {
    __builtin_amdgcn_global_load_lds(
        (const __attribute__((address_space(1))) void*)g,
        (__attribute__((address_space(3))) void*)l, 16, 0, 0);
}

__device__ __forceinline__ void to_xyxy(float x, float y, float w, float h,
                                        float gi, float gj, float o[4]) {
    float cx = mul_rn(64.0f, add_rn(x, gi));
    float cy = mul_rn(64.0f, add_rn(y, gj));
    float W  = mul_rn(w, 448.0f);
    float H  = mul_rn(h, 448.0f);
    float Wh = mul_rn(W, 0.5f);
    float Hh = mul_rn(H, 0.5f);
    o[0] = sub_rn(cx, Wh);
    o[1] = sub_rn(cy, Hh);
    o[2] = add_rn(cx, Wh);
    o[3] = add_rn(cy, Hh);
    if (x == 0.0f && y == 0.0f && w == 0.0f && h == 0.0f) {
        o[0] = o[1] = o[2] = o[3] = 0.0f;
    }
}

__device__ __forceinline__ float iou_box(const float pb[5] /* conf,x,y,w,h */,
                                         const float gb[4], float areag,
                                         float gi, float gj) {
    float p[4];
    to_xyxy(pb[1], pb[2], pb[3], pb[4], gi, gj, p);
    float lx = fmaxf(gb[0], p[0]);
    float ly = fmaxf(gb[1], p[1]);
    float rx = fminf(gb[2], p[2]);
    float ry = fminf(gb[3], p[3]);
    float iw = fmaxf(sub_rn(rx, lx), 0.0f);
    float ih = fmaxf(sub_rn(ry, ly), 0.0f);
    float inter = mul_rn(iw, ih);
    float areap = mul_rn(sub_rn(p[2], p[0]), sub_rn(p[3], p[1]));
    float denom = sub_rn(add_rn(areag, areap), inter);  // left-to-right, as numpy
    return __fdiv_rn(inter, denom);
}

// R4 structure (proven fastest; three different pipelines all converge to the
// same ~5.9 TB/s logical service rate) + fused last-block ticket reduction
// to remove the second kernel launch + its latency.
__global__ __launch_bounds__(TPB, 5) void yolo_main(const float* __restrict__ pred,
                                                    const float* __restrict__ gt,
                                                    float* __restrict__ out,
                                                    float* __restrict__ partials,
                                                    unsigned int* __restrict__ ticket,
                                                    int nblocks, float inv_b) {
    __shared__ float spred[CPB * PRED_CH];  // 15360 B
    __shared__ float sgt[CPB * GT_CH];      // 12800 B
    __shared__ float wsum[TPB / 64];
    __shared__ int is_last;

    const int tid  = threadIdx.x;
    const int lane = tid & 63;
    const int wb   = tid & ~63;            // wave base: 0,64,128,192
    const int cell = blockIdx.x * CPB + tid;   // valid for tid < CPB (grid exact)

    // ---- stage both tiles, fully async; wave-uniform clamped starts, no
    //      branches (duplicate windows rewrite identical bytes — benign) ----
    {
        const float4* ps = reinterpret_cast<const float4*>(pred) + (size_t)blockIdx.x * PF4;
        float4* sp4 = reinterpret_cast<float4*>(spred);
#pragma unroll
        for (int k = 0; k < 4; ++k) {      // PF4=960: starts 0,256,512,768 -> clamp 896
            int s = wb + k * TPB; if (s > PF4 - 64) s = PF4 - 64; s += lane;
            load_lds16(ps + s, sp4 + s);
        }
        const float4* gs = reinterpret_cast<const float4*>(gt) + (size_t)blockIdx.x * GF4;
        float4* sg4 = reinterpret_cast<float4*>(sgt);
#pragma unroll
        for (int k = 0; k < 4; ++k) {      // GF4=800: starts 0,256,512,768 -> clamp 736
            int s = wb + k * TPB; if (s > GF4 - 64) s = GF4 - 64; s += lane;
            load_lds16(gs + s, sg4 + s);
        }
    }
    __syncthreads();   // single vmcnt drain + barrier

    float lsum = 0.0f;
    if (tid < CPB) {
        const float* P = &spred[tid * PRED_CH];  // stride 30: 2-way alias, free
        const float* G = &sgt[tid * GT_CH];      // stride 25: conflict-free

        const float gm = (G[20] == 1.0f) ? 1.0f : 0.0f;

        float cl = 0.0f;
#pragma unroll
        for (int c = 0; c < 20; ++c) {
            float d = P[c] - G[c];
            cl = fmaf(d, d, cl);
        }
        lsum = cl * gm;

        // cell = (b*7 + i)*7 + j ; cx uses i (axis1), cy uses j (axis2)
        const int rem = cell % 49;
        const int ii  = rem / 7;
        const float gi = (float)ii;
        const float gj = (float)(rem - ii * 7);

        float gb[4];
        to_xyxy(G[21], G[22], G[23], G[24], gi, gj, gb);
        const float areag = mul_rn(sub_rn(gb[2], gb[0]), sub_rn(gb[3], gb[1]));

        float pb0[5] = {P[20], P[21], P[22], P[23], P[24]};
        float pb1[5] = {P[25], P[26], P[27], P[28], P[29]};
        const float iou0 = iou_box(pb0, gb, areag, gi, gj);
        const float iou1 = iou_box(pb1, gb, areag, gi, gj);

        const int sel = (iou1 > iou0) ? 1 : 0;   // numpy argmax: first max wins

        out[1 + 2 * (size_t)cell]     = (sel == 0) ? gm : 0.0f;
        out[1 + 2 * (size_t)cell + 1] = (sel == 1) ? gm : 0.0f;
    }

    // ---- block reduce class loss -> partial store + ticket ----
#pragma unroll
    for (int off = 32; off > 0; off >>= 1) lsum += __shfl_down(lsum, off);
    if (lane == 0) wsum[tid >> 6] = lsum;
    __syncthreads();
    if (tid == 0) {
        partials[blockIdx.x] = wsum[0] + wsum[1] + wsum[2] + wsum[3];
        __threadfence();                         // device-scope release
        unsigned int t = atomicAdd(ticket, 1u);  // device-scope RMW
        is_last = (t == (unsigned int)(nblocks - 1)) ? 1 : 0;
    }
    __syncthreads();

    // ---- last block: fixed-order reduction of all partials -> out[0] ----
    if (is_last) {
        __threadfence();                         // acquire side
        float s = 0.0f;
        for (int i = tid; i < nblocks; i += TPB) s += partials[i];
#pragma unroll
        for (int off = 32; off > 0; off >>= 1) s += __shfl_down(s, off);
        if (lane == 0) wsum[tid >> 6] = s;
        __syncthreads();
        if (tid == 0) out[0] = (wsum[0] + wsum[1] + wsum[2] + wsum[3]) * inv_b;
    }
}

extern "C" void kernel_launch(void* const* d_in, const int* in_sizes, int n_in,
                              void* d_out, int out_size, void* d_ws, size_t ws_size,
                              hipStream_t stream) {
    const float* pred = (const float*)d_in[0];
    const float* gt   = (const float*)d_in[1];
    float* out = (float*)d_out;

    unsigned int* ticket = (unsigned int*)d_ws;            // 4 B (zeroed per call)
    float* partials = (float*)((char*)d_ws + 256);         // nblocks floats

    const int ncells = in_sizes[0] / PRED_CH;   // 802816 = 6272 tiles of 128
    const int batch  = ncells / 49;
    const int blocks = ncells / CPB;            // 6272 (exact)

    hipMemsetAsync(d_ws, 0, sizeof(unsigned int), stream);  // reset ticket
    yolo_main<<<blocks, TPB, 0, stream>>>(pred, gt, out, partials, ticket,
                                          blocks, 1.0f / (float)batch);
}

// Round 8
// 34.110 us; speedup vs baseline: 7.0570x; 7.0570x over previous
//
#include <hip/hip_runtime.h>

#define TPB 256
#define CPB 128                     // cells per block
#define PRED_CH 30
#define GT_CH 25
#define PF4 (CPB * PRED_CH / 4)     // 960 float4 per pred tile
#define GF4 (CPB * GT_CH / 4)       // 800 float4 per gt tile

// IEEE-exact helpers: prevent fma contraction so the IoU chain matches numpy
// float32 bit-for-bit (argmax flips would cost absmax=1.0 on obj_ij).
__device__ __forceinline__ float mul_rn(float a, float b) { return __fmul_rn(a, b); }
__device__ __forceinline__ float add_rn(float a, float b) { return __fadd_rn(a, b); }
__device__ __forceinline__ float sub_rn(float a, float b) { return __fsub_rn(a, b); }

// async global->LDS, 16B per lane (wave-uniform base + lane*16 dest — the
// HW-supported pattern, m104).
__device__ __forceinline__ void load_lds16(const void* g, void* l) {
    __builtin_amdgcn_global_load_lds(
        (const __attribute__((address_space(1))) void*)g,
        (__attribute__((address_space(3))) void*)l, 16, 0, 0);
}

__device__ __forceinline__ void to_xyxy(float x, float y, float w, float h,
                                        float gi, float gj, float o[4]) {
    float cx = mul_rn(64.0f, add_rn(x, gi));
    float cy = mul_rn(64.0f, add_rn(y, gj));
    float W  = mul_rn(w, 448.0f);
    float H  = mul_rn(h, 448.0f);
    float Wh = mul_rn(W, 0.5f);
    float Hh = mul_rn(H, 0.5f);
    o[0] = sub_rn(cx, Wh);
    o[1] = sub_rn(cy, Hh);
    o[2] = add_rn(cx, Wh);
    o[3] = add_rn(cy, Hh);
    if (x == 0.0f && y == 0.0f && w == 0.0f && h == 0.0f) {
        o[0] = o[1] = o[2] = o[3] = 0.0f;
    }
}

__device__ __forceinline__ float iou_box(const float pb[5] /* conf,x,y,w,h */,
                                         const float gb[4], float areag,
                                         float gi, float gj) {
    float p[4];
    to_xyxy(pb[1], pb[2], pb[3], pb[4], gi, gj, p);
    float lx = fmaxf(gb[0], p[0]);
    float ly = fmaxf(gb[1], p[1]);
    float rx = fminf(gb[2], p[2]);
    float ry = fminf(gb[3], p[3]);
    float iw = fmaxf(sub_rn(rx, lx), 0.0f);
    float ih = fmaxf(sub_rn(ry, ly), 0.0f);
    float inter = mul_rn(iw, ih);
    float areap = mul_rn(sub_rn(p[2], p[0]), sub_rn(p[3], p[1]));
    float denom = sub_rn(add_rn(areag, areap), inter);  // left-to-right, as numpy
    return __fdiv_rn(inter, denom);
}

// R4 structure — the proven fastest (34.9 us). One async staging phase, one
// barrier, half-block compute, per-block partial store, separate tiny reduce
// kernel. R7's fused last-block reduction (per-block __threadfence + 6272
// same-address atomics) serialized cross-XCD at ~38 ns each = 240 us — on
// 8-XCD parts grid-wide reduction MUST stay in a second kernel.
__global__ __launch_bounds__(TPB, 5) void yolo_main(const float* __restrict__ pred,
                                                    const float* __restrict__ gt,
                                                    float* __restrict__ out,
                                                    float* __restrict__ partials,
                                                    int ncells) {
    __shared__ float spred[CPB * PRED_CH];  // 15360 B
    __shared__ float sgt[CPB * GT_CH];      // 12800 B
    __shared__ float wsum[TPB / 64];

    const int tid  = threadIdx.x;
    const int lane = tid & 63;
    const int wb   = tid & ~63;                // wave base: 0,64,128,192
    const int cell = blockIdx.x * CPB + tid;   // valid for tid < CPB (grid exact)

    // ---- stage both tiles, fully async; wave-uniform clamped starts, no
    //      branches (duplicate windows rewrite identical bytes — benign) ----
    {
        const float4* ps = reinterpret_cast<const float4*>(pred) + (size_t)blockIdx.x * PF4;
        float4* sp4 = reinterpret_cast<float4*>(spred);
#pragma unroll
        for (int k = 0; k < 4; ++k) {      // PF4=960: starts 0,256,512,768 -> clamp 896
            int s = wb + k * TPB; if (s > PF4 - 64) s = PF4 - 64; s += lane;
            load_lds16(ps + s, sp4 + s);
        }
        const float4* gs = reinterpret_cast<const float4*>(gt) + (size_t)blockIdx.x * GF4;
        float4* sg4 = reinterpret_cast<float4*>(sgt);
#pragma unroll
        for (int k = 0; k < 4; ++k) {      // GF4=800: starts 0,256,512,768 -> clamp 736
            int s = wb + k * TPB; if (s > GF4 - 64) s = GF4 - 64; s += lane;
            load_lds16(gs + s, sg4 + s);
        }
    }
    __syncthreads();   // single vmcnt drain + barrier

    float lsum = 0.0f;
    if (tid < CPB) {
        const float* P = &spred[tid * PRED_CH];  // stride 30: 2-way alias, free
        const float* G = &sgt[tid * GT_CH];      // stride 25: conflict-free

        const float gm = (G[20] == 1.0f) ? 1.0f : 0.0f;

        float cl = 0.0f;
#pragma unroll
        for (int c = 0; c < 20; ++c) {
            float d = P[c] - G[c];
            cl = fmaf(d, d, cl);
        }
        lsum = cl * gm;

        // cell = (b*7 + i)*7 + j ; cx uses i (axis1), cy uses j (axis2)
        const int rem = cell % 49;
        const int ii  = rem / 7;
        const float gi = (float)ii;
        const float gj = (float)(rem - ii * 7);

        float gb[4];
        to_xyxy(G[21], G[22], G[23], G[24], gi, gj, gb);
        const float areag = mul_rn(sub_rn(gb[2], gb[0]), sub_rn(gb[3], gb[1]));

        float pb0[5] = {P[20], P[21], P[22], P[23], P[24]};
        float pb1[5] = {P[25], P[26], P[27], P[28], P[29]};
        const float iou0 = iou_box(pb0, gb, areag, gi, gj);
        const float iou1 = iou_box(pb1, gb, areag, gi, gj);

        const int sel = (iou1 > iou0) ? 1 : 0;   // numpy argmax: first max wins

        out[1 + 2 * (size_t)cell]     = (sel == 0) ? gm : 0.0f;
        out[1 + 2 * (size_t)cell + 1] = (sel == 1) ? gm : 0.0f;
    }

    // ---- block reduce class loss; ONE plain store per block (no atomics) ----
#pragma unroll
    for (int off = 32; off > 0; off >>= 1) lsum += __shfl_down(lsum, off);
    if (lane == 0) wsum[tid >> 6] = lsum;
    __syncthreads();
    if (tid == 0) {
        partials[blockIdx.x] = wsum[0] + wsum[1] + wsum[2] + wsum[3];
    }
}

// Single-block fixed-order reduction of per-block partials -> out[0].
// 1024 threads, 4-way accumulator unroll: ~6 loads/thread, short dep chains.
__global__ __launch_bounds__(1024) void yolo_reduce(const float* __restrict__ partials,
                                                    float* __restrict__ out,
                                                    int nblocks, float inv_b) {
    __shared__ float w[16];
    float a0 = 0.0f, a1 = 0.0f, a2 = 0.0f, a3 = 0.0f;
    int i = threadIdx.x;
    for (; i + 3 * 1024 < nblocks; i += 4 * 1024) {
        a0 += partials[i];
        a1 += partials[i + 1024];
        a2 += partials[i + 2048];
        a3 += partials[i + 3072];
    }
    for (; i < nblocks; i += 1024) a0 += partials[i];
    float s = (a0 + a1) + (a2 + a3);
#pragma unroll
    for (int off = 32; off > 0; off >>= 1) s += __shfl_down(s, off);
    if ((threadIdx.x & 63) == 0) w[threadIdx.x >> 6] = s;
    __syncthreads();
    if (threadIdx.x == 0) {
        float t = 0.0f;
#pragma unroll
        for (int k = 0; k < 16; ++k) t += w[k];
        out[0] = t * inv_b;
    }
}

extern "C" void kernel_launch(void* const* d_in, const int* in_sizes, int n_in,
                              void* d_out, int out_size, void* d_ws, size_t ws_size,
                              hipStream_t stream) {
    const float* pred = (const float*)d_in[0];
    const float* gt   = (const float*)d_in[1];
    float* out      = (float*)d_out;
    float* partials = (float*)d_ws;

    const int ncells = in_sizes[0] / PRED_CH;   // 802816 = 6272 tiles of 128
    const int batch  = ncells / 49;
    const int blocks = ncells / CPB;            // 6272 (exact)

    yolo_main<<<blocks, TPB, 0, stream>>>(pred, gt, out, partials, ncells);
    yolo_reduce<<<1, 1024, 0, stream>>>(partials, out, blocks, 1.0f / (float)batch);
}